// Round 2
// baseline (294.633 us; speedup 1.0000x reference)
//
#include <hip/hip_runtime.h>
#include <hip/hip_bf16.h>
#include <math.h>

#define IN_DIM 512
#define HID    1024
#define NE     16
#define T_TOK  8192
#define NPAIR  (T_TOK*2)

typedef __attribute__((ext_vector_type(8))) short bf16x8;
typedef __attribute__((ext_vector_type(4))) float f32x4;

__device__ __forceinline__ unsigned short f2b(float f){
  unsigned u = __float_as_uint(f);
  u += 0x7FFF + ((u >> 16) & 1);           // round-to-nearest-even
  return (unsigned short)(u >> 16);
}
__device__ __forceinline__ float b2f(unsigned short u){
  return __uint_as_float(((unsigned)u) << 16);
}

// Barrier WITHOUT the vmcnt(0) drain __syncthreads() forces.
__device__ __forceinline__ void barrier_lds_only(){
  asm volatile("s_waitcnt lgkmcnt(0)" ::: "memory");
  __builtin_amdgcn_s_barrier();
}

// global -> LDS direct DMA, 16 B per lane. LDS dest is wave-uniform base + lane*16.
typedef const __attribute__((address_space(1))) unsigned int* gas1_t;
typedef __attribute__((address_space(3))) unsigned int* las3_t;
__device__ __forceinline__ void gl16(const unsigned short* g, unsigned short* l){
  __builtin_amdgcn_global_load_lds((gas1_t)(const void*)g, (las3_t)(void*)l, 16, 0, 0);
}

// ---------------- prep: batched transpose+convert, W1 and W2 fused in one launch ----
__global__ __launch_bounds__(256) void tconv2_kernel(const float* __restrict__ A1,
                                                     unsigned short* __restrict__ O1,
                                                     const float* __restrict__ A2,
                                                     unsigned short* __restrict__ O2){
  __shared__ float tile[32][33];
  int b = blockIdx.x;
  const float* src; unsigned short* dst; int M, N, m0, n0;
  if (b < 8192){
    M = IN_DIM; N = HID;
    int e = b >> 9, r = b & 511;              // 32 x 16 tiles per expert
    n0 = (r & 31)*32; m0 = (r >> 5)*32;
    src = A1 + (size_t)e*M*N; dst = O1 + (size_t)e*M*N;
  } else {
    int b2 = b - 8192;
    M = HID; N = IN_DIM;
    int e = b2 >> 9, r = b2 & 511;            // 16 x 32 tiles per expert
    n0 = (r & 15)*32; m0 = (r >> 4)*32;
    src = A2 + (size_t)e*M*N; dst = O2 + (size_t)e*M*N;
  }
  int c = threadIdx.x & 31, r = threadIdx.x >> 5;
  #pragma unroll
  for (int i=0;i<4;i++)
    tile[r + i*8][c] = src[(size_t)(m0 + r + i*8)*N + n0 + c];
  __syncthreads();
  int tr  = threadIdx.x >> 3;
  int tc4 = (threadIdx.x & 7) * 4;
  ushort4 o;
  o.x = f2b(tile[tc4+0][tr]); o.y = f2b(tile[tc4+1][tr]);
  o.z = f2b(tile[tc4+2][tr]); o.w = f2b(tile[tc4+3][tr]);
  *(ushort4*)(&dst[(size_t)(n0 + tr)*M + m0 + tc4]) = o;
}

// ---------------- router: one wave per token; NO global atomics ----------------
__global__ __launch_bounds__(256) void router_kernel(
    const float* __restrict__ x, const float* __restrict__ Wr, const float* __restrict__ br,
    unsigned short* __restrict__ xb, int* __restrict__ eid, float* __restrict__ pw)
{
  int wid = threadIdx.x >> 6, lane = threadIdx.x & 63;
  int t = blockIdx.x*4 + wid;
  const float4* xr4 = (const float4*)(x + (size_t)t*IN_DIM);
  ushort4*      xb4 = (ushort4*)(xb + (size_t)t*IN_DIM);

  float acc[NE];
  #pragma unroll
  for (int i=0;i<NE;i++) acc[i]=0.f;

  #pragma unroll
  for (int j=0;j<2;j++){
    int f = j*64 + lane;
    float4 v = xr4[f];
    ushort4 o; o.x=f2b(v.x); o.y=f2b(v.y); o.z=f2b(v.z); o.w=f2b(v.w);
    xb4[f] = o;
    const float4* wr4 = (const float4*)(Wr + (size_t)(f*4)*NE);
    const float* vv = (const float*)&v;
    #pragma unroll
    for (int rr=0; rr<4; rr++){
      float xv = vv[rr];
      #pragma unroll
      for (int q=0;q<4;q++){
        float4 w = wr4[rr*4+q];
        acc[q*4+0] += xv*w.x; acc[q*4+1] += xv*w.y;
        acc[q*4+2] += xv*w.z; acc[q*4+3] += xv*w.w;
      }
    }
  }
  #pragma unroll
  for (int off=32; off>=1; off>>=1){
    #pragma unroll
    for (int i=0;i<NE;i++) acc[i] += __shfl_xor(acc[i], off, 64);
  }
  if (lane==0){
    #pragma unroll
    for (int i=0;i<NE;i++) acc[i] += br[i];
    int e0=0; float l0=acc[0];
    #pragma unroll
    for (int i=1;i<NE;i++) if (acc[i] > l0){ l0=acc[i]; e0=i; }
    int e1=-1; float l1=-3.0e38f;
    #pragma unroll
    for (int i=0;i<NE;i++) if (i!=e0 && acc[i] > l1){ l1=acc[i]; e1=i; }
    float w0 = 1.f/(1.f + __expf(l1 - l0));
    float w1 = 1.f - w0;
    pw[t*2+0] = w0; pw[t*2+1] = w1;
    eid[t*2+0] = e0; eid[t*2+1] = e1;
  }
}

// ---------------- bucket build: 16 blocks (one per expert), ballot-compact ----------
__global__ __launch_bounds__(1024) void bucket_kernel(const int* __restrict__ eid,
                                                      int* __restrict__ cnt,
                                                      int* __restrict__ bucket){
  int e = blockIdx.x;
  __shared__ int lbase;
  if (threadIdx.x == 0) lbase = 0;
  __syncthreads();
  int lane = threadIdx.x & 63, wid = threadIdx.x >> 6;
  int* be = bucket + e*T_TOK;
  for (int c = wid*64; c < NPAIR; c += 1024){
    int p = c + lane;
    bool ok = (eid[p] == e);
    unsigned long long m = __ballot(ok);
    int rank = __popcll(m & ((1ull << lane) - 1ull));
    int count = __popcll(m);
    int base = 0;
    if (lane == 0) base = atomicAdd(&lbase, count);
    base = __shfl(base, 0, 64);
    if (ok) be[base + rank] = p;
  }
  __syncthreads();
  if (threadIdx.x == 0) cnt[e] = lbase;
}

// ---------------- PERSISTENT grouped GEMM, R11: 256-row tiles, 8 waves, 2-phase ----
// Geometry per the verified 256-tile regime (m230/m248: 2ph=655-682 TF grouped):
//   BM=256, BK=64, 512 threads (8 waves). GEMM1: BN=256, wave grid 2Mx4N (wave tile
//   128x64, acc[8][4]). GEMM2: BN=128, wave grid 4Mx2N (wave tile 64x64, acc[4][4]).
//   LDS = 2buf x (A 32KB + B 32/16KB) = 128/96 KB -> 1 block/CU.
// Staging: global_load_lds width-16; LDS rows are 128B; bank-conflict-free fragment
//   reads via XOR swizzle (slot ^= row&7) applied by PRE-SWIZZLING the per-lane
//   GLOBAL source chunk (m173): LDS slot s of row r holds global chunk s^(r&7);
//   fragment read uses chunk (kk*4+fb)^(fr&7)  -> 2-way conflicts only (free, m136).
// Loop = T3-minimum 2-phase: STAGE(next) issued BEFORE ds_read+MFMA of cur; single
//   vmcnt(0)+lgkmcnt(0)+barrier per K-tile. T1 XCD swizzle on tile index.
// FIRST: A rows gathered via bucket (per-lane global addr); out hb in bucket order.
// !FIRST: A rows sequential (ebase+pos); out opb[pair] scaled by pw (no atomics).

#define STAGE(BUF, KT) do{ \
      _Pragma("unroll") \
      for (int j=0;j<4;j++) \
        gl16(Ag[j] + (KT)*BK, lds + (BUF)*ASZ + wid*2048 + j*512); \
      _Pragma("unroll") \
      for (int j=0;j<NBJ_B;j++) \
        gl16(Bg[j] + (KT)*BK, lds + 2*ASZ + (BUF)*BSZ + wid*(NBJ_B*512) + j*512); \
    }while(0)

#define COMPUTE(BUF) do{ \
      const unsigned short* lcA = lds + (BUF)*ASZ; \
      const unsigned short* lcB = lds + 2*ASZ + (BUF)*BSZ; \
      _Pragma("unroll") \
      for (int kk=0; kk<2; kk++){ \
        const int ch = ((kk*4 + fb) ^ (fr & 7)) * 8; \
        bf16x8 af[SA], bfr[SU]; \
        _Pragma("unroll") \
        for (int s=0;s<SA;s++) af[s]  = *(const bf16x8*)(lcA + (wm + s*16 + fr)*BK + ch); \
        _Pragma("unroll") \
        for (int u=0;u<SU;u++) bfr[u] = *(const bf16x8*)(lcB + (wn + u*16 + fr)*BK + ch); \
        _Pragma("unroll") \
        for (int s=0;s<SA;s++) \
          _Pragma("unroll") \
          for (int u=0;u<SU;u++) \
            acc[s][u] = __builtin_amdgcn_mfma_f32_16x16x32_bf16(af[s], bfr[u], acc[s][u], 0,0,0); \
      } \
    }while(0)

template<int KDIM, int NDIM, int BN, int WGN, bool FIRST>
__global__ __launch_bounds__(512, 2) void moe_gemm(
    const unsigned short* __restrict__ A,
    const unsigned short* __restrict__ Bm,    // [E][NDIM][KDIM] bf16 (pre-transposed)
    const float* __restrict__ bias,           // [E][NDIM]
    const int* __restrict__ cnt,
    const int* __restrict__ bucket,
    const float* __restrict__ pw,
    unsigned short* __restrict__ hb,          // FIRST: out (bucket-order) / !FIRST: in
    unsigned short* __restrict__ opb)         // !FIRST: out (pair rows)
{
  constexpr int BK  = 64;
  constexpr int NS  = KDIM / BK;              // 8 (GEMM1) / 16 (GEMM2), K-tiles
  constexpr int NBT = NDIM / BN;              // 4 n-tiles per expert (both)
  constexpr int WGM = 8 / WGN;
  constexpr int SA  = (256/WGM)/16;           // 8 / 4
  constexpr int SU  = (BN/WGN)/16;            // 4 / 4
  constexpr int ASZ = 256*BK;                 // 16384 shorts (32 KB)
  constexpr int BSZ = BN*BK;                  // 16384 / 8192 shorts
  constexpr int NBJ_B = BN/64;                // B stage instrs per thread: 4 / 2

  int ntiles = 0;
  #pragma unroll
  for (int j=0;j<NE;j++) ntiles += ((cnt[j]+255)>>8)*NBT;

  __shared__ unsigned short lds[2*ASZ + 2*BSZ];   // 128 KB / 96 KB

  const int tid  = threadIdx.x;
  const int lane = tid & 63, wid = tid >> 6;
  const int rsub = lane >> 3;                 // row-within-8 for staging
  const int cs   = ((lane & 7) ^ rsub) * 8;   // pre-swizzled global source chunk (shorts)
  const int fr = lane & 15, fb = lane >> 4, fq = fb*4;
  const int wm = (wid / WGN) * (256/WGM);
  const int wn = (wid % WGN) * (BN/WGN);

  // T1 XCD swizzle: grid 512 -> XCD x owns tiles [x*64, x*64+64) (i0-fastest order
  // => consecutive tiles share the B n-panel => panel stays in the XCD's L2).
  for (int t = (blockIdx.x & 7)*64 + (blockIdx.x >> 3); t < ntiles; t += gridDim.x){
    // ---- tile -> (e, tloc, ebase, ce, itl) via register scan (no arrays) ----
    int e=0, tloc=0, ebase=0, ce=0, itl=1;
    {
      int cum=0, crow=0;
      #pragma unroll
      for (int j=0;j<NE;j++){
        int cj = cnt[j];
        int it = (cj+255)>>8;
        int tj = it * NBT;
        bool in = (t >= cum) & (t < cum+tj);
        if (in){ e=j; tloc=t-cum; ebase=crow; ce=cj; itl=it; }
        cum += tj; crow += cj;
      }
    }
    const int i0 = (tloc % itl) * 256;        // i0-fastest
    const int n0 = (tloc / itl) * BN;

    const int* buck = bucket + e*T_TOK;
    const unsigned short* Ag[4];
    #pragma unroll
    for (int j=0;j<4;j++){
      int p = i0 + wid*32 + j*8 + rsub;
      int arow;
      if (FIRST){
        arow = buck[(p < ce) ? p : i0] >> 1;
      } else {
        arow = ebase + p; if (arow > NPAIR-1) arow = NPAIR-1;
      }
      Ag[j] = A + (size_t)arow*KDIM + cs;
    }
    const unsigned short* Bg[NBJ_B];
    #pragma unroll
    for (int j=0;j<NBJ_B;j++)
      Bg[j] = Bm + (size_t)e*NDIM*KDIM + (size_t)(n0 + wid*(NBJ_B*8) + j*8 + rsub)*KDIM + cs;

    f32x4 acc[SA][SU];
    #pragma unroll
    for (int s=0;s<SA;s++)
      #pragma unroll
      for (int u=0;u<SU;u++)
        #pragma unroll
        for (int j=0;j<4;j++) acc[s][u][j] = 0.f;

    // ---- 2-phase K loop: stage next K-tile, compute current, one drain/barrier ----
    STAGE(0, 0);
    asm volatile("s_waitcnt vmcnt(0)" ::: "memory");
    barrier_lds_only();
    int cur = 0;
    #pragma unroll 1
    for (int kt=0; kt<NS-1; ++kt){
      STAGE(cur^1, kt+1);                     // issue BEFORE compute (overlaps MFMA)
      __builtin_amdgcn_s_setprio(1);
      COMPUTE(cur);
      __builtin_amdgcn_s_setprio(0);
      asm volatile("s_waitcnt vmcnt(0)" ::: "memory");  // next tile landed
      barrier_lds_only();                     // my ds_reads done + all waves synced
      cur ^= 1;
    }
    __builtin_amdgcn_s_setprio(1);
    COMPUTE(cur);
    __builtin_amdgcn_s_setprio(0);
    barrier_lds_only();                       // seal reads before next tile's STAGE

    // ---- epilogue: C/D layout col=lane&15, row=(lane>>4)*4+reg [m89-verified] ----
    const float* be = bias + e*NDIM;
    #pragma unroll
    for (int s=0;s<SA;s++){
      #pragma unroll
      for (int i=0;i<4;i++){
        int row = wm + s*16 + fq + i;
        int pos = i0 + row;
        if (pos >= ce) continue;
        int pair = 0; float pwv = 0.f;
        if (!FIRST){ pair = buck[pos]; pwv = pw[pair]; }
        #pragma unroll
        for (int u=0;u<SU;u++){
          int n = n0 + wn + u*16 + fr;
          float v = acc[s][u][i] + be[n];
          if (FIRST){
            float g = 0.5f*v*(1.f + erff(v*0.70710678118654752f));   // exact GELU
            hb[(size_t)(ebase + pos)*NDIM + n] = f2b(g);
          } else {
            opb[(size_t)pair*NDIM + n] = f2b(pwv*v);
          }
        }
      }
    }
  }
}

#undef COMPUTE
#undef STAGE

// ---------------- combine: out = x + opb[2t] + opb[2t+1] (coalesced) ----------------
__global__ __launch_bounds__(256) void combine_kernel(const float* __restrict__ x,
                                                      const unsigned short* __restrict__ opb,
                                                      float* __restrict__ out){
  int i = blockIdx.x*256 + threadIdx.x;
  int t  = i >> 7;
  int c4 = i & 127;
  float4 v = ((const float4*)x)[i];
  ushort4 a = ((const ushort4*)opb)[(size_t)(2*t)*128 + c4];
  ushort4 b = ((const ushort4*)opb)[(size_t)(2*t+1)*128 + c4];
  v.x += b2f(a.x) + b2f(b.x);
  v.y += b2f(a.y) + b2f(b.y);
  v.z += b2f(a.z) + b2f(b.z);
  v.w += b2f(a.w) + b2f(b.w);
  ((float4*)out)[i] = v;
}

// ---------------- launch ----------------
extern "C" void kernel_launch(void* const* d_in, const int* in_sizes, int n_in,
                              void* d_out, int out_size, void* d_ws, size_t ws_size,
                              hipStream_t stream)
{
  const float* x  = (const float*)d_in[0];
  const float* Wr = (const float*)d_in[1];
  const float* br = (const float*)d_in[2];
  const float* W1 = (const float*)d_in[3];
  const float* b1 = (const float*)d_in[4];
  const float* W2 = (const float*)d_in[5];
  const float* b2 = (const float*)d_in[6];
  float* out = (float*)d_out;
  char* ws = (char*)d_ws;

  // ws layout (bytes) — identical footprint to the passing layout
  int*            cnt    = (int*)(ws + 0);            // 64 B
  int*            bucket = (int*)(ws + 1024);         // 16*8192*4 = 524288
  float*          pw     = (float*)(ws + 525312);     // 16384*4   = 65536
  unsigned short* xb     = (unsigned short*)(ws + 590848);    // 8192*512*2  = 8388608
  unsigned short* w1t    = (unsigned short*)(ws + 8979456);   // 16*512*1024*2 = 16777216
  unsigned short* w2t    = (unsigned short*)(ws + 25756672);  // 16777216
  unsigned short* hb     = (unsigned short*)(ws + 42533888);  // 16384*1024*2 = 33554432
  // aliases (stream-ordered lifetimes):
  //  eid at hb head: router writes, bucket reads, dead before GEMM1 writes hb
  //  opb in w1t region: w1t dead after GEMM1; opb = GEMM2 out, read by combine
  int*            eid    = (int*)(ws + 42533888);     // 16384*4 = 65536
  unsigned short* opb    = w1t;                       // 16384*512*2 = 16777216 (exact fit)

  router_kernel<<<T_TOK/4, 256, 0, stream>>>(x, Wr, br, xb, eid, pw);
  bucket_kernel<<<NE, 1024, 0, stream>>>(eid, cnt, bucket);
  tconv2_kernel<<<16384, 256, 0, stream>>>(W1, w1t, W2, w2t);
  moe_gemm<IN_DIM, HID, 256, 4, true ><<<512, 512, 0, stream>>>(
      xb, w1t, b1, cnt, bucket, pw, hb, opb);
  moe_gemm<HID, IN_DIM, 128, 2, false><<<512, 512, 0, stream>>>(
      hb, w2t, b2, cnt, bucket, pw, hb, opb);
  combine_kernel<<<(T_TOK*IN_DIM/4)/256, 256, 0, stream>>>(x, opb, out);
}

// Round 3
// 293.423 us; speedup vs baseline: 1.0041x; 1.0041x over previous
//
#include <hip/hip_runtime.h>
#include <hip/hip_bf16.h>
#include <math.h>

#define IN_DIM 512
#define HID    1024
#define NE     16
#define T_TOK  8192
#define NPAIR  (T_TOK*2)

typedef __attribute__((ext_vector_type(8))) short bf16x8;
typedef __attribute__((ext_vector_type(4))) float f32x4;

__device__ __forceinline__ unsigned short f2b(float f){
  unsigned u = __float_as_uint(f);
  u += 0x7FFF + ((u >> 16) & 1);           // round-to-nearest-even
  return (unsigned short)(u >> 16);
}
__device__ __forceinline__ float b2f(unsigned short u){
  return __uint_as_float(((unsigned)u) << 16);
}

// Barrier WITHOUT the vmcnt(0) drain __syncthreads() forces (R6-verified pattern).
__device__ __forceinline__ void barrier_lds_only(){
  asm volatile("s_waitcnt lgkmcnt(0)" ::: "memory");
  __builtin_amdgcn_s_barrier();
}

// ---------------- prep: batched transpose+convert, W1 and W2 fused in one launch ----
__global__ __launch_bounds__(256) void tconv2_kernel(const float* __restrict__ A1,
                                                     unsigned short* __restrict__ O1,
                                                     const float* __restrict__ A2,
                                                     unsigned short* __restrict__ O2){
  __shared__ float tile[32][33];
  int b = blockIdx.x;
  const float* src; unsigned short* dst; int M, N, m0, n0;
  if (b < 8192){
    M = IN_DIM; N = HID;
    int e = b >> 9, r = b & 511;              // 32 x 16 tiles per expert
    n0 = (r & 31)*32; m0 = (r >> 5)*32;
    src = A1 + (size_t)e*M*N; dst = O1 + (size_t)e*M*N;
  } else {
    int b2 = b - 8192;
    M = HID; N = IN_DIM;
    int e = b2 >> 9, r = b2 & 511;            // 16 x 32 tiles per expert
    n0 = (r & 15)*32; m0 = (r >> 4)*32;
    src = A2 + (size_t)e*M*N; dst = O2 + (size_t)e*M*N;
  }
  int c = threadIdx.x & 31, r = threadIdx.x >> 5;
  #pragma unroll
  for (int i=0;i<4;i++)
    tile[r + i*8][c] = src[(size_t)(m0 + r + i*8)*N + n0 + c];
  __syncthreads();
  int tr  = threadIdx.x >> 3;
  int tc4 = (threadIdx.x & 7) * 4;
  ushort4 o;
  o.x = f2b(tile[tc4+0][tr]); o.y = f2b(tile[tc4+1][tr]);
  o.z = f2b(tile[tc4+2][tr]); o.w = f2b(tile[tc4+3][tr]);
  *(ushort4*)(&dst[(size_t)(n0 + tr)*M + m0 + tc4]) = o;
}

// ---------------- router: one wave per token; NO global atomics ----------------
__global__ __launch_bounds__(256) void router_kernel(
    const float* __restrict__ x, const float* __restrict__ Wr, const float* __restrict__ br,
    unsigned short* __restrict__ xb, int* __restrict__ eid, float* __restrict__ pw)
{
  int wid = threadIdx.x >> 6, lane = threadIdx.x & 63;
  int t = blockIdx.x*4 + wid;
  const float4* xr4 = (const float4*)(x + (size_t)t*IN_DIM);
  ushort4*      xb4 = (ushort4*)(xb + (size_t)t*IN_DIM);

  float acc[NE];
  #pragma unroll
  for (int i=0;i<NE;i++) acc[i]=0.f;

  #pragma unroll
  for (int j=0;j<2;j++){
    int f = j*64 + lane;
    float4 v = xr4[f];
    ushort4 o; o.x=f2b(v.x); o.y=f2b(v.y); o.z=f2b(v.z); o.w=f2b(v.w);
    xb4[f] = o;
    const float4* wr4 = (const float4*)(Wr + (size_t)(f*4)*NE);
    const float* vv = (const float*)&v;
    #pragma unroll
    for (int rr=0; rr<4; rr++){
      float xv = vv[rr];
      #pragma unroll
      for (int q=0;q<4;q++){
        float4 w = wr4[rr*4+q];
        acc[q*4+0] += xv*w.x; acc[q*4+1] += xv*w.y;
        acc[q*4+2] += xv*w.z; acc[q*4+3] += xv*w.w;
      }
    }
  }
  #pragma unroll
  for (int off=32; off>=1; off>>=1){
    #pragma unroll
    for (int i=0;i<NE;i++) acc[i] += __shfl_xor(acc[i], off, 64);
  }
  if (lane==0){
    #pragma unroll
    for (int i=0;i<NE;i++) acc[i] += br[i];
    int e0=0; float l0=acc[0];
    #pragma unroll
    for (int i=1;i<NE;i++) if (acc[i] > l0){ l0=acc[i]; e0=i; }
    int e1=-1; float l1=-3.0e38f;
    #pragma unroll
    for (int i=0;i<NE;i++) if (i!=e0 && acc[i] > l1){ l1=acc[i]; e1=i; }
    float w0 = 1.f/(1.f + __expf(l1 - l0));
    float w1 = 1.f - w0;
    pw[t*2+0] = w0; pw[t*2+1] = w1;
    eid[t*2+0] = e0; eid[t*2+1] = e1;
  }
}

// ---------------- bucket build: 16 blocks (one per expert), ballot-compact ----------
__global__ __launch_bounds__(1024) void bucket_kernel(const int* __restrict__ eid,
                                                      int* __restrict__ cnt,
                                                      int* __restrict__ bucket){
  int e = blockIdx.x;
  __shared__ int lbase;
  if (threadIdx.x == 0) lbase = 0;
  __syncthreads();
  int lane = threadIdx.x & 63, wid = threadIdx.x >> 6;
  int* be = bucket + e*T_TOK;
  for (int c = wid*64; c < NPAIR; c += 1024){
    int p = c + lane;
    bool ok = (eid[p] == e);
    unsigned long long m = __ballot(ok);
    int rank = __popcll(m & ((1ull << lane) - 1ull));
    int count = __popcll(m);
    int base = 0;
    if (lane == 0) base = atomicAdd(&lbase, count);
    base = __shfl(base, 0, 64);
    if (ok) be[base + rank] = p;
  }
  __syncthreads();
  if (threadIdx.x == 0) cnt[e] = lbase;
}

// ---------------- GEMM1 (R12): 128x128 tile, 4 waves of 64x64, R6 schedule ---------
// Same proven reg-staged double-buffer + single lgkm-barrier-per-K-step as R6, but
// 2x wave tile: 16 MFMA per 8 ds_read_b128 per K-step (R6: 8 per 6) -> 1.5x better
// MFMA-per-LDS-byte, half the barriers per FLOP. LDS 32 KB. Swizzle: slot=chunk^key,
// key(row)=(row>>1)&3 (invariant under row+64, so both row-halves share wA offsets);
// read key at row wm+s*16+fr reduces to (fr>>1)&3 = R6's verified pf8. XCD-chunked
// tile swizzle (bijective on grid 1024): consecutive tiles per XCD share B panels.
template<int KDIM, int NDIM, bool FIRST>
__global__ __launch_bounds__(256) void moe_gemm128(
    const unsigned short* __restrict__ A,
    const unsigned short* __restrict__ Bm,    // [E][NDIM][KDIM] bf16 (pre-transposed)
    const float* __restrict__ bias,
    const int* __restrict__ cnt,
    const int* __restrict__ bucket,
    const float* __restrict__ pw,
    unsigned short* __restrict__ hb,
    unsigned short* __restrict__ opb)
{
  constexpr int NS  = KDIM / 32;              // K-steps (16 for KDIM=512)
  constexpr int NBT = NDIM / 128;

  int ntiles = 0;
  #pragma unroll
  for (int j=0;j<NE;j++) ntiles += ((cnt[j]+127)>>7)*NBT;

  __shared__ unsigned short As[2*128*32];     // 16 KB (two buffers)
  __shared__ unsigned short Bs[2*128*32];     // 16 KB

  const int tid  = threadIdx.x;
  const int lane = tid & 63, wid = tid >> 6;
  const int lr0 = tid >> 2;                   // rows lr0 and lr0+64
  const int c   = tid & 3;
  const int sc  = (c ^ ((lr0 >> 1) & 3)) * 8; // XOR-swizzled LDS slot
  const int wA  = lr0*32 + sc;                // row-half 1 at wA + 64*32
  const int fr = lane & 15, fb = lane >> 4;
  const int pf8 = (fb ^ ((fr >> 1) & 3)) * 8;
  const int fq = fb*4;
  const int wm = (wid>>1)*64, wn = (wid&1)*64;

  const int t0 = (blockIdx.x & 7)*128 + (blockIdx.x >> 3);   // XCD-chunked, bijective
  for (int t = t0; t < ntiles; t += gridDim.x){
    // ---- tile -> (e, tloc, ebase, ce, itl) via register scan ----
    int e=0, tloc=0, ebase=0, ce=0, itl=1;
    {
      int cum=0, crow=0;
      #pragma unroll
      for (int j=0;j<NE;j++){
        int cj = cnt[j];
        int it = (cj+127)>>7;
        int tj = it * NBT;
        bool in = (t >= cum) & (t < cum+tj);
        if (in){ e=j; tloc=t-cum; ebase=crow; ce=cj; itl=it; }
        cum += tj; crow += cj;
      }
    }
    const int i0 = (tloc % itl) * 128;        // i0-fastest (B-panel reuse)
    const int n0 = (tloc / itl) * 128;

    const int* buck = bucket + e*T_TOK;
    int p0 = i0 + lr0, p1 = p0 + 64;
    int ar0, ar1;
    if (FIRST){
      ar0 = buck[(p0 < ce) ? p0 : i0] >> 1;
      ar1 = buck[(p1 < ce) ? p1 : i0] >> 1;
    } else {
      ar0 = ebase + p0; if (ar0 > NPAIR-1) ar0 = NPAIR-1;
      ar1 = ebase + p1; if (ar1 > NPAIR-1) ar1 = NPAIR-1;
    }
    const unsigned short* Ag0 = A + (size_t)ar0*KDIM + c*8;
    const unsigned short* Ag1 = A + (size_t)ar1*KDIM + c*8;
    const unsigned short* Bg0 = Bm + (size_t)e*NDIM*KDIM + (size_t)(n0 + lr0)*KDIM + c*8;
    const unsigned short* Bg1 = Bg0 + (size_t)64*KDIM;

    f32x4 acc[4][4];
    #pragma unroll
    for (int s=0;s<4;s++)
      #pragma unroll
      for (int u=0;u<4;u++)
        #pragma unroll
        for (int j=0;j<4;j++) acc[s][u][j] = 0.f;

    // ---- prologue: tile0 -> buf0; regs = tile1 ----
    float4 a0,a1,b0,b1;
    a0 = *(const float4*)(Ag0);
    a1 = *(const float4*)(Ag1);
    b0 = *(const float4*)(Bg0);
    b1 = *(const float4*)(Bg1);
    *(float4*)(As + wA) = a0;
    *(float4*)(As + wA + 64*32) = a1;
    *(float4*)(Bs + wA) = b0;
    *(float4*)(Bs + wA + 64*32) = b1;
    a0 = *(const float4*)(Ag0 + 32);
    a1 = *(const float4*)(Ag1 + 32);
    b0 = *(const float4*)(Bg0 + 32);
    b1 = *(const float4*)(Bg1 + 32);
    barrier_lds_only();

    #pragma unroll 2
    for (int k = 0; k < NS; k++){
      const int cur = k & 1, nxt = cur ^ 1;
      float4 na0,na1,nb0,nb1;
      bool ld = (k + 2 < NS);
      if (ld){
        na0 = *(const float4*)(Ag0 + (k+2)*32);
        na1 = *(const float4*)(Ag1 + (k+2)*32);
        nb0 = *(const float4*)(Bg0 + (k+2)*32);
        nb1 = *(const float4*)(Bg1 + (k+2)*32);
      }
      if (k + 1 < NS){
        *(float4*)(As + nxt*4096 + wA) = a0;
        *(float4*)(As + nxt*4096 + wA + 64*32) = a1;
        *(float4*)(Bs + nxt*4096 + wA) = b0;
        *(float4*)(Bs + nxt*4096 + wA + 64*32) = b1;
      }
      if (ld){ a0=na0; a1=na1; b0=nb0; b1=nb1; }

      const unsigned short* Ac = As + cur*4096;
      const unsigned short* Bc = Bs + cur*4096;
      bf16x8 af[4], bfr[4];
      #pragma unroll
      for (int s=0;s<4;s++) af[s]  = *(const bf16x8*)(Ac + (wm + s*16 + fr)*32 + pf8);
      #pragma unroll
      for (int u=0;u<4;u++) bfr[u] = *(const bf16x8*)(Bc + (wn + u*16 + fr)*32 + pf8);
      #pragma unroll
      for (int s=0;s<4;s++)
        #pragma unroll
        for (int u=0;u<4;u++)
          acc[s][u] = __builtin_amdgcn_mfma_f32_16x16x32_bf16(af[s], bfr[u], acc[s][u], 0,0,0);
      barrier_lds_only();
    }

    // ---- epilogue: C/D layout col=lane&15, row=(lane>>4)*4+reg [m89-verified] ----
    const float* be = bias + e*NDIM;
    #pragma unroll
    for (int s=0;s<4;s++){
      #pragma unroll
      for (int i=0;i<4;i++){
        int row = wm + s*16 + fq + i;
        int pos = i0 + row;
        if (pos >= ce) continue;
        int pair = 0; float pwv = 0.f;
        if (!FIRST){ pair = buck[pos]; pwv = pw[pair]; }
        #pragma unroll
        for (int u=0;u<4;u++){
          int n = n0 + wn + u*16 + fr;
          float v = acc[s][u][i] + be[n];
          if (FIRST){
            float g = 0.5f*v*(1.f + erff(v*0.70710678118654752f));   // exact GELU
            hb[(size_t)(ebase + pos)*NDIM + n] = f2b(g);
          } else {
            opb[(size_t)pair*NDIM + n] = f2b(pwv*v);
          }
        }
      }
    }
  }
}

// ---------------- GEMM2: verbatim R6 64x128 kernel (61 us proven) ------------------
template<int KDIM, int NDIM, bool FIRST>
__global__ __launch_bounds__(256) void moe_gemm(
    const unsigned short* __restrict__ A,
    const unsigned short* __restrict__ Bm,
    const float* __restrict__ bias,
    const int* __restrict__ cnt,
    const int* __restrict__ bucket,
    const float* __restrict__ pw,
    unsigned short* __restrict__ hb,
    unsigned short* __restrict__ opb)
{
  constexpr int NS  = KDIM / 32;
  constexpr int NBT = NDIM / 128;

  int ntiles = 0;
  #pragma unroll
  for (int j=0;j<NE;j++) ntiles += ((cnt[j]+63)>>6)*NBT;

  __shared__ unsigned short As[2*64*32];      //  8 KB
  __shared__ unsigned short Bs[2*128*32];     // 16 KB

  int tid = threadIdx.x;
  int lane = tid & 63, wid = tid >> 6;
  int wm = (wid>>1)*32, wn = (wid&1)*64;
  int lr0 = tid >> 2;
  int c   = tid & 3;
  int sc  = (c ^ ((lr0 >> 1) & 3)) * 8;
  int wA  = lr0*32 + sc;
  int fr = lane & 15, fb = lane >> 4;
  int pf8 = (fb ^ ((fr >> 1) & 3)) * 8;
  int fq = (lane>>4)*4;

  for (int t = blockIdx.x; t < ntiles; t += gridDim.x){
    int e=0, tloc=0, ebase=0, ce=0, itl=1;
    {
      int cum=0, crow=0;
      #pragma unroll
      for (int j=0;j<NE;j++){
        int cj = cnt[j];
        int it = (cj+63)>>6;
        int tj = it * NBT;
        bool in = (t >= cum) & (t < cum+tj);
        if (in){ e=j; tloc=t-cum; ebase=crow; ce=cj; itl=it; }
        cum += tj; crow += cj;
      }
    }
    int i0 = (tloc % itl) * 64;
    int n0 = (tloc / itl) * 128;

    const int* buck = bucket + e*T_TOK;
    int posA = i0 + lr0;
    int arow;
    if (FIRST){
      int pair = (posA < ce) ? buck[posA] : buck[i0];
      arow = pair >> 1;
    } else {
      arow = ebase + posA;
      if (arow > NPAIR-1) arow = NPAIR-1;
    }
    const unsigned short* Ag = A + (size_t)arow*KDIM + c*8;
    const unsigned short* Bg = Bm + (size_t)e*NDIM*KDIM + (size_t)(n0 + lr0)*KDIM + c*8;

    f32x4 acc[2][4];
    #pragma unroll
    for (int a=0;a<2;a++)
      #pragma unroll
      for (int b=0;b<4;b++)
        #pragma unroll
        for (int j=0;j<4;j++) acc[a][b][j] = 0.f;

    float4 ar, br0, br1;
    ar  = *(const float4*)(Ag);
    br0 = *(const float4*)(Bg);
    br1 = *(const float4*)(Bg + (size_t)64*KDIM);
    *(float4*)(As + wA) = ar;
    *(float4*)(Bs + wA) = br0;
    *(float4*)(Bs + wA + 64*32) = br1;
    ar  = *(const float4*)(Ag + 32);
    br0 = *(const float4*)(Bg + 32);
    br1 = *(const float4*)(Bg + (size_t)64*KDIM + 32);
    barrier_lds_only();

    #pragma unroll 2
    for (int k = 0; k < NS; k++){
      const int cur = k & 1, nxt = cur ^ 1;
      float4 na, nb0, nb1;
      bool ld = (k + 2 < NS);
      if (ld){
        na  = *(const float4*)(Ag + (k+2)*32);
        nb0 = *(const float4*)(Bg + (k+2)*32);
        nb1 = *(const float4*)(Bg + (size_t)64*KDIM + (k+2)*32);
      }
      if (k + 1 < NS){
        *(float4*)(As + nxt*2048 + wA) = ar;
        *(float4*)(Bs + nxt*4096 + wA) = br0;
        *(float4*)(Bs + nxt*4096 + wA + 64*32) = br1;
      }
      if (ld){ ar = na; br0 = nb0; br1 = nb1; }

      const unsigned short* Ac = As + cur*2048;
      const unsigned short* Bc = Bs + cur*4096;
      bf16x8 af[2], bfr[4];
      #pragma unroll
      for (int s=0;s<2;s++) af[s]  = *(const bf16x8*)(Ac + (wm + s*16 + fr)*32 + pf8);
      #pragma unroll
      for (int u=0;u<4;u++) bfr[u] = *(const bf16x8*)(Bc + (wn + u*16 + fr)*32 + pf8);
      #pragma unroll
      for (int s=0;s<2;s++)
        #pragma unroll
        for (int u=0;u<4;u++)
          acc[s][u] = __builtin_amdgcn_mfma_f32_16x16x32_bf16(af[s], bfr[u], acc[s][u], 0,0,0);
      barrier_lds_only();
    }

    #pragma unroll
    for (int s=0;s<2;s++){
      #pragma unroll
      for (int i=0;i<4;i++){
        int row = wm + s*16 + fq + i;
        int pos = i0 + row;
        if (pos >= ce) continue;
        #pragma unroll
        for (int u=0;u<4;u++){
          int n = n0 + wn + u*16 + fr;
          float v = acc[s][u][i] + bias[e*NDIM + n];
          if (FIRST){
            float g = 0.5f*v*(1.f + erff(v*0.70710678118654752f));
            hb[(size_t)(ebase + pos)*NDIM + n] = f2b(g);
          } else {
            int pair = buck[pos];
            opb[(size_t)pair*NDIM + n] = f2b(pw[pair]*v);
          }
        }
      }
    }
  }
}

// ---------------- combine: out = x + opb[2t] + opb[2t+1] (coalesced) ----------------
__global__ __launch_bounds__(256) void combine_kernel(const float* __restrict__ x,
                                                      const unsigned short* __restrict__ opb,
                                                      float* __restrict__ out){
  int i = blockIdx.x*256 + threadIdx.x;
  int t  = i >> 7;
  int c4 = i & 127;
  float4 v = ((const float4*)x)[i];
  ushort4 a = ((const ushort4*)opb)[(size_t)(2*t)*128 + c4];
  ushort4 b = ((const ushort4*)opb)[(size_t)(2*t+1)*128 + c4];
  v.x += b2f(a.x) + b2f(b.x);
  v.y += b2f(a.y) + b2f(b.y);
  v.z += b2f(a.z) + b2f(b.z);
  v.w += b2f(a.w) + b2f(b.w);
  ((float4*)out)[i] = v;
}

// ---------------- launch ----------------
extern "C" void kernel_launch(void* const* d_in, const int* in_sizes, int n_in,
                              void* d_out, int out_size, void* d_ws, size_t ws_size,
                              hipStream_t stream)
{
  const float* x  = (const float*)d_in[0];
  const float* Wr = (const float*)d_in[1];
  const float* br = (const float*)d_in[2];
  const float* W1 = (const float*)d_in[3];
  const float* b1 = (const float*)d_in[4];
  const float* W2 = (const float*)d_in[5];
  const float* b2 = (const float*)d_in[6];
  float* out = (float*)d_out;
  char* ws = (char*)d_ws;

  // ws layout (bytes) — identical footprint to the passing layout
  int*            cnt    = (int*)(ws + 0);            // 64 B
  int*            bucket = (int*)(ws + 1024);         // 16*8192*4 = 524288
  float*          pw     = (float*)(ws + 525312);     // 16384*4   = 65536
  unsigned short* xb     = (unsigned short*)(ws + 590848);    // 8192*512*2  = 8388608
  unsigned short* w1t    = (unsigned short*)(ws + 8979456);   // 16*512*1024*2 = 16777216
  unsigned short* w2t    = (unsigned short*)(ws + 25756672);  // 16777216
  unsigned short* hb     = (unsigned short*)(ws + 42533888);  // 16384*1024*2 = 33554432
  // aliases (stream-ordered lifetimes):
  //  eid at hb head: router writes, bucket reads, dead before GEMM1 writes hb
  //  opb in w1t region: w1t dead after GEMM1; opb = GEMM2 out, read by combine
  int*            eid    = (int*)(ws + 42533888);     // 16384*4 = 65536
  unsigned short* opb    = w1t;                       // 16384*512*2 = 16777216 (exact fit)

  router_kernel<<<T_TOK/4, 256, 0, stream>>>(x, Wr, br, xb, eid, pw);
  bucket_kernel<<<NE, 1024, 0, stream>>>(eid, cnt, bucket);
  tconv2_kernel<<<16384, 256, 0, stream>>>(W1, w1t, W2, w2t);
  moe_gemm128<IN_DIM, HID, true ><<<1024, 256, 0, stream>>>(
      xb, w1t, b1, cnt, bucket, pw, hb, opb);
  moe_gemm<HID, IN_DIM, false><<<1024, 256, 0, stream>>>(
      hb, w2t, b2, cnt, bucket, pw, hb, opb);
  combine_kernel<<<(T_TOK*IN_DIM/4)/256, 256, 0, stream>>>(x, opb, out);
}

// Round 4
// 249.972 us; speedup vs baseline: 1.1787x; 1.1738x over previous
//
#include <hip/hip_runtime.h>
#include <hip/hip_bf16.h>
#include <math.h>

#define IN_DIM 512
#define HID    1024
#define NE     16
#define T_TOK  8192
#define NPAIR  (T_TOK*2)

typedef __attribute__((ext_vector_type(8))) short bf16x8;
typedef __attribute__((ext_vector_type(8))) unsigned short ushort8;
typedef __attribute__((ext_vector_type(4))) float f32x4;

__device__ __forceinline__ unsigned short f2b(float f){
  unsigned u = __float_as_uint(f);
  u += 0x7FFF + ((u >> 16) & 1);           // round-to-nearest-even
  return (unsigned short)(u >> 16);
}
__device__ __forceinline__ float b2f(unsigned short u){
  return __uint_as_float(((unsigned)u) << 16);
}

// Barrier WITHOUT the vmcnt(0) drain __syncthreads() forces (R6-verified pattern).
__device__ __forceinline__ void barrier_lds_only(){
  asm volatile("s_waitcnt lgkmcnt(0)" ::: "memory");
  __builtin_amdgcn_s_barrier();
}

// ---------------- fused head: router (blocks 0..2047) + 64x64 transpose-convert ----
// tconv W1: blocks [2048,4096): [E][512][1024] f32 -> [E][1024][512] bf16
// tconv W2: blocks [4096,6144): [E][1024][512] f32 -> [E][512][1024] bf16
// 64x64 tiles, float4 loads (256B/row-wave), ushort8 stores (128B/row/8lanes),
// LDS pad 65 -> 2-way banking only (free, m136). Router hides under tconv.
__global__ __launch_bounds__(256) void fused_head(
    const float* __restrict__ x, const float* __restrict__ Wr, const float* __restrict__ br,
    unsigned short* __restrict__ xb, int* __restrict__ eid, float* __restrict__ pw,
    const float* __restrict__ W1, unsigned short* __restrict__ O1,
    const float* __restrict__ W2, unsigned short* __restrict__ O2)
{
  __shared__ float tile[64][65];
  const int b = blockIdx.x;
  const int tid = threadIdx.x;

  if (b < 2048){
    // ---- router: one wave per token; NO global atomics (verbatim R6 body) ----
    int wid = tid >> 6, lane = tid & 63;
    int t = b*4 + wid;
    const float4* xr4 = (const float4*)(x + (size_t)t*IN_DIM);
    ushort4*      xb4 = (ushort4*)(xb + (size_t)t*IN_DIM);

    float acc[NE];
    #pragma unroll
    for (int i=0;i<NE;i++) acc[i]=0.f;

    #pragma unroll
    for (int j=0;j<2;j++){
      int f = j*64 + lane;
      float4 v = xr4[f];
      ushort4 o; o.x=f2b(v.x); o.y=f2b(v.y); o.z=f2b(v.z); o.w=f2b(v.w);
      xb4[f] = o;
      const float4* wr4 = (const float4*)(Wr + (size_t)(f*4)*NE);
      const float* vv = (const float*)&v;
      #pragma unroll
      for (int rr=0; rr<4; rr++){
        float xv = vv[rr];
        #pragma unroll
        for (int q=0;q<4;q++){
          float4 w = wr4[rr*4+q];
          acc[q*4+0] += xv*w.x; acc[q*4+1] += xv*w.y;
          acc[q*4+2] += xv*w.z; acc[q*4+3] += xv*w.w;
        }
      }
    }
    #pragma unroll
    for (int off=32; off>=1; off>>=1){
      #pragma unroll
      for (int i=0;i<NE;i++) acc[i] += __shfl_xor(acc[i], off, 64);
    }
    if (lane==0){
      #pragma unroll
      for (int i=0;i<NE;i++) acc[i] += br[i];
      int e0=0; float l0=acc[0];
      #pragma unroll
      for (int i=1;i<NE;i++) if (acc[i] > l0){ l0=acc[i]; e0=i; }
      int e1=-1; float l1=-3.0e38f;
      #pragma unroll
      for (int i=0;i<NE;i++) if (i!=e0 && acc[i] > l1){ l1=acc[i]; e1=i; }
      float w0 = 1.f/(1.f + __expf(l1 - l0));
      float w1 = 1.f - w0;
      pw[t*2+0] = w0; pw[t*2+1] = w1;
      eid[t*2+0] = e0; eid[t*2+1] = e1;
    }
    return;
  }

  // ---- tconv 64x64 ----
  const float* src; unsigned short* dst; int M, N, m0, n0;
  if (b < 4096){
    int b1 = b - 2048; M = IN_DIM; N = HID;
    int e = b1 >> 7, r = b1 & 127;            // 8 m-tiles x 16 n-tiles
    n0 = (r & 15)*64; m0 = (r >> 4)*64;
    src = W1 + (size_t)e*M*N; dst = O1 + (size_t)e*M*N;
  } else {
    int b2 = b - 4096; M = HID; N = IN_DIM;
    int e = b2 >> 7, r = b2 & 127;            // 16 m-tiles x 8 n-tiles
    n0 = (r & 7)*64; m0 = (r >> 3)*64;
    src = W2 + (size_t)e*M*N; dst = O2 + (size_t)e*M*N;
  }
  const int lr = tid >> 4, lc = (tid & 15)*4;
  #pragma unroll
  for (int i=0;i<4;i++)
    *(float4*)&tile[lr + i*16][lc] = *(const float4*)&src[(size_t)(m0 + lr + i*16)*N + n0 + lc];
  __syncthreads();
  const int nr = tid >> 3, mc = (tid & 7)*8;
  #pragma unroll
  for (int p=0;p<2;p++){
    int n = nr + p*32;
    ushort8 o;
    #pragma unroll
    for (int j=0;j<8;j++) o[j] = f2b(tile[mc+j][n]);
    *(ushort8*)&dst[(size_t)(n0 + n)*M + m0 + mc] = o;
  }
}

// ---------------- bucket build: 16 blocks (one per expert), ballot-compact ----------
__global__ __launch_bounds__(1024) void bucket_kernel(const int* __restrict__ eid,
                                                      int* __restrict__ cnt,
                                                      int* __restrict__ bucket){
  int e = blockIdx.x;
  __shared__ int lbase;
  if (threadIdx.x == 0) lbase = 0;
  __syncthreads();
  int lane = threadIdx.x & 63, wid = threadIdx.x >> 6;
  int* be = bucket + e*T_TOK;
  for (int c = wid*64; c < NPAIR; c += 1024){
    int p = c + lane;
    bool ok = (eid[p] == e);
    unsigned long long m = __ballot(ok);
    int rank = __popcll(m & ((1ull << lane) - 1ull));
    int count = __popcll(m);
    int base = 0;
    if (lane == 0) base = atomicAdd(&lbase, count);
    base = __shfl(base, 0, 64);
    if (ok) be[base + rank] = p;
  }
  __syncthreads();
  if (threadIdx.x == 0) cnt[e] = lbase;
}

// ---------------- PERSISTENT grouped GEMM: verbatim R6 61us structure + 2 edits ----
// Edit 1: XCD-chunked bijective tile swizzle (R12-proven: FETCH 100->24 MB, no cost).
// Edit 2: tanh-form GELU, g = v*sigmoid(2z), z2 = v*(1.59577 + 0.0713548*v^2).
//   Max deviation from exact erf-GELU ~5e-4 << bf16 quantization of hb (~8e-3).
// Everything else (schedule, swizzle, layouts, barriers) untouched.
template<int KDIM, int NDIM, bool FIRST>
__global__ __launch_bounds__(256) void moe_gemm(
    const unsigned short* __restrict__ A,
    const unsigned short* __restrict__ Bm,    // [E][NDIM][KDIM] bf16 (pre-transposed)
    const float* __restrict__ bias,           // [E][NDIM]
    const int* __restrict__ cnt,
    const int* __restrict__ bucket,
    const float* __restrict__ pw,
    unsigned short* __restrict__ hb,          // FIRST: out (bucket-order) / !FIRST: in
    unsigned short* __restrict__ opb)         // !FIRST: out (pair rows)
{
  constexpr int NS  = KDIM / 32;              // K-steps per tile
  constexpr int NBT = NDIM / 128;             // n-tiles per expert

  int ntiles = 0;
  #pragma unroll
  for (int j=0;j<NE;j++) ntiles += ((cnt[j]+63)>>6)*NBT;

  __shared__ unsigned short As[2*64*32];      //  8 KB (two buffers)
  __shared__ unsigned short Bs[2*128*32];     // 16 KB

  int tid = threadIdx.x;
  int lane = tid & 63, wid = tid >> 6;
  int wm = (wid>>1)*32, wn = (wid&1)*64;
  int lr0 = tid >> 2;
  int c   = tid & 3;
  int sc  = (c ^ ((lr0 >> 1) & 3)) * 8;       // XOR-swizzled LDS col (R6: 0 conflicts)
  int wA  = lr0*32 + sc;
  int fr = lane & 15, fb = lane >> 4;
  int pf8 = (fb ^ ((fr >> 1) & 3)) * 8;
  int fq = (lane>>4)*4;

  // XCD-chunked bijective swizzle: consecutive tiles per XCD share the B n-panel.
  const int t0 = (blockIdx.x & 7)*(gridDim.x >> 3) + (blockIdx.x >> 3);
  for (int t = t0; t < ntiles; t += gridDim.x){
    // ---- tile -> (e, tloc, ebase, ce, itl) via register scan (no arrays) ----
    int e=0, tloc=0, ebase=0, ce=0, itl=1;
    {
      int cum=0, crow=0;
      #pragma unroll
      for (int j=0;j<NE;j++){
        int cj = cnt[j];
        int it = (cj+63)>>6;
        int tj = it * NBT;
        bool in = (t >= cum) & (t < cum+tj);
        if (in){ e=j; tloc=t-cum; ebase=crow; ce=cj; itl=it; }
        cum += tj; crow += cj;
      }
    }
    int i0 = (tloc % itl) * 64;               // i0-fastest ordering
    int n0 = (tloc / itl) * 128;

    const int* buck = bucket + e*T_TOK;
    int posA = i0 + lr0;
    int arow;
    if (FIRST){
      int pair = (posA < ce) ? buck[posA] : buck[i0];
      arow = pair >> 1;
    } else {
      arow = ebase + posA;                    // sequential bucket-order row
      if (arow > NPAIR-1) arow = NPAIR-1;     // tail guard (stores epilogue-guarded)
    }
    const unsigned short* Ag = A + (size_t)arow*KDIM + c*8;
    const unsigned short* Bg = Bm + (size_t)e*NDIM*KDIM + (size_t)(n0 + lr0)*KDIM + c*8;

    f32x4 acc[2][4];
    #pragma unroll
    for (int a=0;a<2;a++)
      #pragma unroll
      for (int b=0;b<4;b++)
        #pragma unroll
        for (int j=0;j<4;j++) acc[a][b][j] = 0.f;

    // ---- prologue: tile0 -> buf0; regs = tile1 ----
    float4 ar, br0, br1;
    ar  = *(const float4*)(Ag);
    br0 = *(const float4*)(Bg);
    br1 = *(const float4*)(Bg + (size_t)64*KDIM);
    *(float4*)(As + wA) = ar;
    *(float4*)(Bs + wA) = br0;
    *(float4*)(Bs + wA + 64*32) = br1;
    ar  = *(const float4*)(Ag + 32);
    br0 = *(const float4*)(Bg + 32);
    br1 = *(const float4*)(Bg + (size_t)64*KDIM + 32);
    barrier_lds_only();

    #pragma unroll 2
    for (int k = 0; k < NS; k++){
      const int cur = k & 1, nxt = cur ^ 1;
      float4 na, nb0, nb1;
      bool ld = (k + 2 < NS);
      if (ld){
        na  = *(const float4*)(Ag + (k+2)*32);
        nb0 = *(const float4*)(Bg + (k+2)*32);
        nb1 = *(const float4*)(Bg + (size_t)64*KDIM + (k+2)*32);
      }
      if (k + 1 < NS){
        *(float4*)(As + nxt*2048 + wA) = ar;
        *(float4*)(Bs + nxt*4096 + wA) = br0;
        *(float4*)(Bs + nxt*4096 + wA + 64*32) = br1;
      }
      if (ld){ ar = na; br0 = nb0; br1 = nb1; }

      const unsigned short* Ac = As + cur*2048;
      const unsigned short* Bc = Bs + cur*4096;
      bf16x8 af[2], bfr[4];
      #pragma unroll
      for (int s=0;s<2;s++) af[s]  = *(const bf16x8*)(Ac + (wm + s*16 + fr)*32 + pf8);
      #pragma unroll
      for (int u=0;u<4;u++) bfr[u] = *(const bf16x8*)(Bc + (wn + u*16 + fr)*32 + pf8);
      #pragma unroll
      for (int s=0;s<2;s++)
        #pragma unroll
        for (int u=0;u<4;u++)
          acc[s][u] = __builtin_amdgcn_mfma_f32_16x16x32_bf16(af[s], bfr[u], acc[s][u], 0,0,0);
      barrier_lds_only();   // after this, all waves' LDS ops done -> next tile may restage
    }

    // ---- epilogue: C/D layout col=lane&15, row=(lane>>4)*4+reg [m89-verified] ----
    #pragma unroll
    for (int s=0;s<2;s++){
      #pragma unroll
      for (int i=0;i<4;i++){
        int row = wm + s*16 + fq + i;
        int pos = i0 + row;
        if (pos >= ce) continue;
        #pragma unroll
        for (int u=0;u<4;u++){
          int n = n0 + wn + u*16 + fr;
          float v = acc[s][u][i] + bias[e*NDIM + n];
          if (FIRST){
            // tanh-GELU: g = v * sigmoid(2*0.79788456*(v + 0.044715 v^3))
            float z2 = v*(1.5957691216057308f + 0.0713548162726009f*v*v);
            float g  = __fdividef(v, 1.f + __expf(-z2));
            hb[(size_t)(ebase + pos)*NDIM + n] = f2b(g);
          } else {
            int pair = buck[pos];
            opb[(size_t)pair*NDIM + n] = f2b(pw[pair]*v);
          }
        }
      }
    }
  }
}

// ---------------- combine: out = x + opb[2t] + opb[2t+1] (coalesced) ----------------
__global__ __launch_bounds__(256) void combine_kernel(const float* __restrict__ x,
                                                      const unsigned short* __restrict__ opb,
                                                      float* __restrict__ out){
  int i = blockIdx.x*256 + threadIdx.x;
  int t  = i >> 7;
  int c4 = i & 127;
  float4 v = ((const float4*)x)[i];
  ushort4 a = ((const ushort4*)opb)[(size_t)(2*t)*128 + c4];
  ushort4 b = ((const ushort4*)opb)[(size_t)(2*t+1)*128 + c4];
  v.x += b2f(a.x) + b2f(b.x);
  v.y += b2f(a.y) + b2f(b.y);
  v.z += b2f(a.z) + b2f(b.z);
  v.w += b2f(a.w) + b2f(b.w);
  ((float4*)out)[i] = v;
}

// ---------------- launch ----------------
extern "C" void kernel_launch(void* const* d_in, const int* in_sizes, int n_in,
                              void* d_out, int out_size, void* d_ws, size_t ws_size,
                              hipStream_t stream)
{
  const float* x  = (const float*)d_in[0];
  const float* Wr = (const float*)d_in[1];
  const float* br = (const float*)d_in[2];
  const float* W1 = (const float*)d_in[3];
  const float* b1 = (const float*)d_in[4];
  const float* W2 = (const float*)d_in[5];
  const float* b2 = (const float*)d_in[6];
  float* out = (float*)d_out;
  char* ws = (char*)d_ws;

  // ws layout (bytes) — identical footprint to the passing layout
  int*            cnt    = (int*)(ws + 0);            // 64 B
  int*            bucket = (int*)(ws + 1024);         // 16*8192*4 = 524288
  float*          pw     = (float*)(ws + 525312);     // 16384*4   = 65536
  unsigned short* xb     = (unsigned short*)(ws + 590848);    // 8192*512*2  = 8388608
  unsigned short* w1t    = (unsigned short*)(ws + 8979456);   // 16*512*1024*2 = 16777216
  unsigned short* w2t    = (unsigned short*)(ws + 25756672);  // 16777216
  unsigned short* hb     = (unsigned short*)(ws + 42533888);  // 16384*1024*2 = 33554432
  // aliases (stream-ordered lifetimes):
  //  eid at hb head: router writes, bucket reads, dead before GEMM1 writes hb
  //  opb in w1t region: w1t dead after GEMM1; opb = GEMM2 out, read by combine
  int*            eid    = (int*)(ws + 42533888);     // 16384*4 = 65536
  unsigned short* opb    = w1t;                       // 16384*512*2 = 16777216 (exact fit)

  fused_head<<<6144, 256, 0, stream>>>(x, Wr, br, xb, eid, pw, W1, w1t, W2, w2t);
  bucket_kernel<<<NE, 1024, 0, stream>>>(eid, cnt, bucket);
  moe_gemm<IN_DIM, HID, true ><<<1024, 256, 0, stream>>>(
      xb, w1t, b1, cnt, bucket, pw, hb, opb);
  moe_gemm<HID, IN_DIM, false><<<1024, 256, 0, stream>>>(
      hb, w2t, b2, cnt, bucket, pw, hb, opb);
  combine_kernel<<<(T_TOK*IN_DIM/4)/256, 256, 0, stream>>>(x, opb, out);
}